// Round 1
// baseline (11205.962 us; speedup 1.0000x reference)
//
#include <hip/hip_runtime.h>
#include <hip/hip_bf16.h>
#include <math.h>

// Problem constants
#define SEQ   2048
#define VOC   50257
#define EMB   512
#define HID   768
#define G3    2304      // 3*HID
#define MDIM  256
#define CSZ   64
#define NCHUNK 32
#define UDIM  2048
#define E4    2048      // 4*EMB

#define G_GRU 48        // GRU workgroups; 2304 rows / 48 = 48 rows (16 units x 3 gates) each

// ---------------------------------------------------------------------------
// Embedding gather: X[s][e] = emb[ids[s]][e]
// ---------------------------------------------------------------------------
__global__ __launch_bounds__(256) void embed_kernel(const int* __restrict__ ids,
                                                    const float* __restrict__ emb,
                                                    float* __restrict__ X) {
    int s = blockIdx.x;
    int id = ids[s];
    const float* src = &emb[(size_t)id * EMB];
    float* dst = &X[(size_t)s * EMB];
    for (int i = threadIdx.x; i < EMB; i += 256) dst[i] = src[i];
}

// ---------------------------------------------------------------------------
// Generic fp32 GEMM:  C[M,N] = A[M,K] @ B[N,K]^T + bias[N]   (both row-major,
// dot along contiguous K).  128x128 tile, BK=16, 256 threads, 8x8 per thread.
// EPI: 0 = none, 1 = relu^2 (for head).
// ---------------------------------------------------------------------------
template<int EPI>
__global__ __launch_bounds__(256) void gemm_nt(const float* __restrict__ A,
                                               const float* __restrict__ B,
                                               const float* __restrict__ bias,
                                               float* __restrict__ C,
                                               int M, int N, int K) {
    __shared__ float As[16][132];
    __shared__ float Bs[16][132];
    const int tid = threadIdx.x;
    const int tx = tid & 15;        // 0..15 -> N direction
    const int ty = tid >> 4;        // 0..15 -> M direction
    const int m0 = blockIdx.y * 128;
    const int n0 = blockIdx.x * 128;

    float acc[8][8];
    #pragma unroll
    for (int i = 0; i < 8; i++)
        #pragma unroll
        for (int j = 0; j < 8; j++) acc[i][j] = 0.f;

    for (int k0 = 0; k0 < K; k0 += 16) {
        // stage A and B tiles (128 rows x 16 cols each), 2 float4 per thread each
        #pragma unroll
        for (int i = 0; i < 2; i++) {
            int idx = tid * 2 + i;          // 0..511
            int r   = idx >> 2;             // 0..127
            int c4  = idx & 3;              // which float4 within the 16 cols
            float4 av = {0.f, 0.f, 0.f, 0.f};
            float4 bv = {0.f, 0.f, 0.f, 0.f};
            int ar = m0 + r;
            if (ar < M) av = *reinterpret_cast<const float4*>(&A[(size_t)ar * K + k0 + c4 * 4]);
            int br = n0 + r;
            if (br < N) bv = *reinterpret_cast<const float4*>(&B[(size_t)br * K + k0 + c4 * 4]);
            As[c4 * 4 + 0][r] = av.x; As[c4 * 4 + 1][r] = av.y;
            As[c4 * 4 + 2][r] = av.z; As[c4 * 4 + 3][r] = av.w;
            Bs[c4 * 4 + 0][r] = bv.x; Bs[c4 * 4 + 1][r] = bv.y;
            Bs[c4 * 4 + 2][r] = bv.z; Bs[c4 * 4 + 3][r] = bv.w;
        }
        __syncthreads();
        #pragma unroll
        for (int k = 0; k < 16; k++) {
            float4 a0 = *reinterpret_cast<const float4*>(&As[k][ty * 4]);
            float4 a1 = *reinterpret_cast<const float4*>(&As[k][64 + ty * 4]);
            float4 b0 = *reinterpret_cast<const float4*>(&Bs[k][tx * 4]);
            float4 b1 = *reinterpret_cast<const float4*>(&Bs[k][64 + tx * 4]);
            float a[8] = {a0.x, a0.y, a0.z, a0.w, a1.x, a1.y, a1.z, a1.w};
            float b[8] = {b0.x, b0.y, b0.z, b0.w, b1.x, b1.y, b1.z, b1.w};
            #pragma unroll
            for (int i = 0; i < 8; i++)
                #pragma unroll
                for (int j = 0; j < 8; j++)
                    acc[i][j] = fmaf(a[i], b[j], acc[i][j]);
        }
        __syncthreads();
    }

    #pragma unroll
    for (int i = 0; i < 8; i++) {
        int r = m0 + ((i < 4) ? (ty * 4 + i) : (64 + ty * 4 + (i - 4)));
        if (r >= M) continue;
        #pragma unroll
        for (int j = 0; j < 8; j++) {
            int c = n0 + ((j < 4) ? (tx * 4 + j) : (64 + tx * 4 + (j - 4)));
            if (c >= N) continue;
            float v = acc[i][j] + bias[c];
            if (EPI == 1) { v = fmaxf(v, 0.f); v = v * v; }
            C[(size_t)r * N + c] = v;
        }
    }
}

// ---------------------------------------------------------------------------
// Persistent GRU kernel. 48 WGs x 256 threads. WG g owns hidden units
// [16g, 16g+16): rows {u, 768+u, 1536+u} of W_hh, held in LDS (padded rows).
// Per step: gh slice -> gates -> write own 16 h values -> device-scope flag
// barrier -> reload full h. Flags are monotone counters (memset per launch).
// ---------------------------------------------------------------------------
#define WPAD 776   // 768 + 8 pad: breaks bank clustering across ty rows

__global__ __launch_bounds__(256) void gru_kernel(const float* __restrict__ GX,
                                                  const float* __restrict__ Whh,
                                                  const float* __restrict__ bhh,
                                                  float* __restrict__ states,
                                                  unsigned* __restrict__ flags) {
    extern __shared__ float smem[];
    float* Ws   = smem;                  // 48 * WPAD
    float* h_s  = Ws + 48 * WPAD;        // 768
    float* sums = h_s + 768;             // 48
    float* bhhs = sums + 48;             // 48
    float* gxs  = bhhs + 48;             // 48

    const int tid = threadIdx.x;
    const int g   = blockIdx.x;          // 0..47
    const int tx  = tid & 15;            // k-slice
    const int ty  = tid >> 4;            // row within batch-of-16

    // Load W_hh slice: local row w (w = gate*16 + unit) -> global row gate*768 + 16g + unit
    for (int i = tid; i < 48 * 768; i += 256) {
        int w = i / 768, k = i - w * 768;
        int gr = (w >> 4) * HID + g * 16 + (w & 15);
        Ws[w * WPAD + k] = Whh[(size_t)gr * HID + k];
    }
    if (tid < 48) {
        int gr = (tid >> 4) * HID + g * 16 + (tid & 15);
        bhhs[tid] = bhh[gr];
    }
    for (int i = tid; i < HID; i += 256) h_s[i] = 0.f;
    __syncthreads();

    for (int t = 0; t < SEQ; t++) {
        // prefetch this step's gx values (independent of h -> hides latency)
        float gxv = 0.f;
        if (tid < 48) {
            int gr = (tid >> 4) * HID + g * 16 + (tid & 15);
            gxv = GX[(size_t)t * G3 + gr];
        }
        // per-thread h slice (reused across the 3 gate batches)
        float4 h4[12];
        #pragma unroll
        for (int j = 0; j < 12; j++)
            h4[j] = *reinterpret_cast<const float4*>(&h_s[4 * tx + 64 * j]);

        float accp[3];
        #pragma unroll
        for (int p = 0; p < 3; p++) {
            const float* wr = &Ws[(p * 16 + ty) * WPAD + 4 * tx];
            float a = 0.f;
            #pragma unroll
            for (int j = 0; j < 12; j++) {
                float4 wv = *reinterpret_cast<const float4*>(&wr[64 * j]);
                a = fmaf(wv.x, h4[j].x, a);
                a = fmaf(wv.y, h4[j].y, a);
                a = fmaf(wv.z, h4[j].z, a);
                a = fmaf(wv.w, h4[j].w, a);
            }
            accp[p] = a;
        }
        if (tid < 48) gxs[tid] = gxv;
        #pragma unroll
        for (int p = 0; p < 3; p++) {
            float a = accp[p];
            a += __shfl_xor(a, 1);
            a += __shfl_xor(a, 2);
            a += __shfl_xor(a, 4);
            a += __shfl_xor(a, 8);
            if (tx == 0) sums[p * 16 + ty] = a;
        }
        __syncthreads();

        if (tid < 16) {
            int u = tid;
            float hr = sums[u]      + bhhs[u];
            float hz = sums[16 + u] + bhhs[16 + u];
            float hn = sums[32 + u] + bhhs[32 + u];
            float xr = gxs[u], xz = gxs[16 + u], xn = gxs[32 + u];
            float r = 1.f / (1.f + expf(-(xr + hr)));
            float z = 1.f / (1.f + expf(-(xz + hz)));
            float n = tanhf(xn + r * hn);
            float hp = h_s[g * 16 + u];
            float hv = (1.f - z) * n + z * hp;
            states[(size_t)t * HID + g * 16 + u] = hv;
        }
        __syncthreads();

        // device-scope barrier: release own flag, acquire-poll all flags
        if (tid == 0)
            __hip_atomic_store(&flags[g * 16], (unsigned)(t + 1),
                               __ATOMIC_RELEASE, __HIP_MEMORY_SCOPE_AGENT);
        if (tid < G_GRU) {
            while (__hip_atomic_load(&flags[tid * 16],
                                     __ATOMIC_ACQUIRE, __HIP_MEMORY_SCOPE_AGENT)
                   < (unsigned)(t + 1)) {}
        }
        __syncthreads();

        // reload full h_t
        for (int i = tid; i < HID; i += 256)
            h_s[i] = states[(size_t)t * HID + i];
        __syncthreads();
    }
}

// ---------------------------------------------------------------------------
// chunked[c][e] = mean over 64 steps
// ---------------------------------------------------------------------------
__global__ __launch_bounds__(256) void chunkmean_kernel(const float* __restrict__ states,
                                                        float* __restrict__ chunked) {
    int c = blockIdx.x;
    for (int e = threadIdx.x; e < HID; e += 256) {
        float s = 0.f;
        #pragma unroll 8
        for (int i = 0; i < CSZ; i++)
            s += states[(size_t)(c * CSZ + i) * HID + e];
        chunked[c * HID + e] = s * (1.f / 64.f);
    }
}

// ---------------------------------------------------------------------------
// attention: scores[s][c] = dot(qk[s], mk[c])/16, causal chunk mask, softmax
// ---------------------------------------------------------------------------
__global__ void attn_kernel(const float* __restrict__ qk,
                            const float* __restrict__ mk,
                            float* __restrict__ attn) {
    int s = blockIdx.x;
    int lane = threadIdx.x;      // 64 threads
    int c = lane & 31;
    int h = lane >> 5;           // 0/1: split K
    const float* q = &qk[(size_t)s * MDIM];
    const float* m = &mk[(size_t)c * MDIM];
    float sc = 0.f;
    for (int k = h; k < MDIM; k += 2) sc = fmaf(q[k], m[k], sc);
    sc += __shfl_xor(sc, 32);
    sc *= (1.0f / 16.0f);        // 1/sqrt(256)
    bool allowed = (CSZ * c + (CSZ - 1)) < s;
    float v = allowed ? sc : -3.4e38f;
    float mx = v;
    #pragma unroll
    for (int d = 16; d >= 1; d >>= 1) mx = fmaxf(mx, __shfl_xor(mx, d));
    float e = (allowed && mx > -1e37f) ? expf(sc - mx) : 0.f;
    float sm = e;
    #pragma unroll
    for (int d = 16; d >= 1; d >>= 1) sm += __shfl_xor(sm, d);
    float a = (sm > 0.f) ? e / sm : 0.f;
    if (lane < 32) attn[(size_t)s * NCHUNK + c] = a;
}

// ---------------------------------------------------------------------------
// total_partial = base_partial + attn @ chunk_partial; scatter-add into out
// ---------------------------------------------------------------------------
__global__ __launch_bounds__(256) void total_scatter_kernel(const float* __restrict__ bp,
                                                            const float* __restrict__ cp,
                                                            const float* __restrict__ attn,
                                                            const int* __restrict__ uids,
                                                            float* __restrict__ out) {
    int s = blockIdx.x;
    __shared__ float a_s[NCHUNK];
    if (threadIdx.x < NCHUNK) a_s[threadIdx.x] = attn[(size_t)s * NCHUNK + threadIdx.x];
    __syncthreads();
    for (int u = threadIdx.x; u < UDIM; u += 256) {
        float t = bp[(size_t)s * UDIM + u];
        #pragma unroll 8
        for (int c = 0; c < NCHUNK; c++)
            t = fmaf(a_s[c], cp[(size_t)c * UDIM + u], t);
        atomicAdd(&out[(size_t)s * VOC + uids[u]], t);
    }
}

// ---------------------------------------------------------------------------
// launch
// ---------------------------------------------------------------------------
extern "C" void kernel_launch(void* const* d_in, const int* in_sizes, int n_in,
                              void* d_out, int out_size, void* d_ws, size_t ws_size,
                              hipStream_t stream) {
    const int*   ids   = (const int*)d_in[0];
    const int*   uids  = (const int*)d_in[1];
    const float* emb   = (const float*)d_in[2];
    const float* w_ih  = (const float*)d_in[3];
    const float* w_hh  = (const float*)d_in[4];
    const float* b_ih  = (const float*)d_in[5];
    const float* b_hh  = (const float*)d_in[6];
    const float* Wq    = (const float*)d_in[7];
    const float* bq    = (const float*)d_in[8];
    const float* Wk    = (const float*)d_in[9];
    const float* bk    = (const float*)d_in[10];
    const float* Whf   = (const float*)d_in[11];
    const float* bhf   = (const float*)d_in[12];
    const float* Whp   = (const float*)d_in[13];
    const float* bhp   = (const float*)d_in[14];
    const float* Wcv   = (const float*)d_in[15];
    const float* bcv   = (const float*)d_in[16];
    const float* Wph   = (const float*)d_in[17];
    const float* bph   = (const float*)d_in[18];
    const float* obias = (const float*)d_in[19];
    float* out = (float*)d_out;
    float* wsf = (float*)d_ws;

    // workspace layout (floats)
    size_t off = 0;
    float* X      = wsf + off; off += (size_t)SEQ * EMB;       // 2048*512
    float* GX     = wsf + off; off += (size_t)SEQ * G3;        // 2048*2304
    float* states = wsf + off; off += (size_t)SEQ * HID;       // 2048*768
    float* head   = wsf + off; off += (size_t)SEQ * E4;        // 2048*2048
    float* bfeat  = wsf + off; off += (size_t)SEQ * EMB;       // 2048*512
    float* chunk  = wsf + off; off += (size_t)NCHUNK * HID;    // 32*768
    float* qk     = wsf + off; off += (size_t)SEQ * MDIM;      // 2048*256
    float* mk     = wsf + off; off += (size_t)NCHUNK * MDIM;   // 32*256
    float* cv     = wsf + off; off += (size_t)NCHUNK * EMB;    // 32*512
    float* cp     = wsf + off; off += (size_t)NCHUNK * UDIM;   // 32*2048
    float* bp     = wsf + off; off += (size_t)SEQ * UDIM;      // 2048*2048
    float* attn   = wsf + off; off += (size_t)SEQ * NCHUNK;    // 2048*32
    unsigned* flags = (unsigned*)(wsf + off);                  // 48*16 u32

    constexpr size_t GRU_LDS = (48 * WPAD + HID + 48 + 48 + 48) * sizeof(float);
    (void)hipFuncSetAttribute((const void*)gru_kernel,
                              hipFuncAttributeMaxDynamicSharedMemorySize, (int)GRU_LDS);

    // 1) embedding gather
    embed_kernel<<<SEQ, 256, 0, stream>>>(ids, emb, X);
    // 2) GX = X @ w_ih^T + b_ih   [2048, 2304], K=512
    gemm_nt<0><<<dim3(G3 / 128, SEQ / 128), 256, 0, stream>>>(X, w_ih, b_ih, GX, SEQ, G3, EMB);
    // 3) reset barrier flags, run GRU
    hipMemsetAsync(flags, 0, G_GRU * 16 * sizeof(unsigned), stream);
    gru_kernel<<<G_GRU, 256, GRU_LDS, stream>>>(GX, w_hh, b_hh, states, flags);
    // 4) chunk means
    chunkmean_kernel<<<NCHUNK, 256, 0, stream>>>(states, chunk);
    // 5) projections
    gemm_nt<0><<<dim3(MDIM / 128, SEQ / 128), 256, 0, stream>>>(states, Wq, bq, qk, SEQ, MDIM, HID);
    gemm_nt<0><<<dim3(MDIM / 128, 1), 256, 0, stream>>>(chunk, Wk, bk, mk, NCHUNK, MDIM, HID);
    gemm_nt<1><<<dim3(E4 / 128, SEQ / 128), 256, 0, stream>>>(states, Whf, bhf, head, SEQ, E4, HID);
    gemm_nt<0><<<dim3(EMB / 128, SEQ / 128), 256, 0, stream>>>(head, Whp, bhp, bfeat, SEQ, EMB, E4);
    gemm_nt<0><<<dim3(EMB / 128, 1), 256, 0, stream>>>(chunk, Wcv, bcv, cv, NCHUNK, EMB, HID);
    gemm_nt<0><<<dim3(UDIM / 128, 1), 256, 0, stream>>>(cv, Wph, bph, cp, NCHUNK, UDIM, EMB);
    gemm_nt<0><<<dim3(UDIM / 128, SEQ / 128), 256, 0, stream>>>(bfeat, Wph, bph, bp, SEQ, UDIM, EMB);
    // 6) base_logits -> d_out (full overwrite each call)
    gemm_nt<0><<<dim3((VOC + 127) / 128, SEQ / 128), 256, 0, stream>>>(bfeat, emb, obias, out, SEQ, VOC, EMB);
    // 7) attention weights
    attn_kernel<<<SEQ, 64, 0, stream>>>(qk, mk, attn);
    // 8) total partial + scatter-add
    total_scatter_kernel<<<SEQ, 256, 0, stream>>>(bp, cp, attn, uids, out);
}

// Round 2
// 6874.297 us; speedup vs baseline: 1.6301x; 1.6301x over previous
//
#include <hip/hip_runtime.h>
#include <hip/hip_bf16.h>
#include <math.h>

// Problem constants
#define SEQ   2048
#define VOC   50257
#define EMB   512
#define HID   768
#define G3    2304      // 3*HID
#define MDIM  256
#define CSZ   64
#define NCHUNK 32
#define UDIM  2048
#define E4    2048      // 4*EMB

#define G_GRU 48        // GRU workgroups; each owns 16 hidden units (48 rows of W_hh)
#define CANARY 0xFFFFFFFFu   // -NaN bit pattern; GRU h is always finite => unreachable

// ---------------------------------------------------------------------------
// Embedding gather: X[s][e] = emb[ids[s]][e]
// ---------------------------------------------------------------------------
__global__ __launch_bounds__(256) void embed_kernel(const int* __restrict__ ids,
                                                    const float* __restrict__ emb,
                                                    float* __restrict__ X) {
    int s = blockIdx.x;
    int id = ids[s];
    const float* src = &emb[(size_t)id * EMB];
    float* dst = &X[(size_t)s * EMB];
    for (int i = threadIdx.x; i < EMB; i += 256) dst[i] = src[i];
}

// ---------------------------------------------------------------------------
// Generic fp32 GEMM:  C[M,N] = A[M,K] @ B[N,K]^T + bias[N]   (both row-major,
// dot along contiguous K).  128x128 tile, BK=16, 256 threads, 8x8 per thread.
// EPI: 0 = none, 1 = relu^2 (for head).
// ---------------------------------------------------------------------------
template<int EPI>
__global__ __launch_bounds__(256) void gemm_nt(const float* __restrict__ A,
                                               const float* __restrict__ B,
                                               const float* __restrict__ bias,
                                               float* __restrict__ C,
                                               int M, int N, int K) {
    __shared__ float As[16][132];
    __shared__ float Bs[16][132];
    const int tid = threadIdx.x;
    const int tx = tid & 15;        // 0..15 -> N direction
    const int ty = tid >> 4;        // 0..15 -> M direction
    const int m0 = blockIdx.y * 128;
    const int n0 = blockIdx.x * 128;

    float acc[8][8];
    #pragma unroll
    for (int i = 0; i < 8; i++)
        #pragma unroll
        for (int j = 0; j < 8; j++) acc[i][j] = 0.f;

    for (int k0 = 0; k0 < K; k0 += 16) {
        #pragma unroll
        for (int i = 0; i < 2; i++) {
            int idx = tid * 2 + i;          // 0..511
            int r   = idx >> 2;             // 0..127
            int c4  = idx & 3;              // which float4 within the 16 cols
            float4 av = {0.f, 0.f, 0.f, 0.f};
            float4 bv = {0.f, 0.f, 0.f, 0.f};
            int ar = m0 + r;
            if (ar < M) av = *reinterpret_cast<const float4*>(&A[(size_t)ar * K + k0 + c4 * 4]);
            int br = n0 + r;
            if (br < N) bv = *reinterpret_cast<const float4*>(&B[(size_t)br * K + k0 + c4 * 4]);
            As[c4 * 4 + 0][r] = av.x; As[c4 * 4 + 1][r] = av.y;
            As[c4 * 4 + 2][r] = av.z; As[c4 * 4 + 3][r] = av.w;
            Bs[c4 * 4 + 0][r] = bv.x; Bs[c4 * 4 + 1][r] = bv.y;
            Bs[c4 * 4 + 2][r] = bv.z; Bs[c4 * 4 + 3][r] = bv.w;
        }
        __syncthreads();
        #pragma unroll
        for (int k = 0; k < 16; k++) {
            float4 a0 = *reinterpret_cast<const float4*>(&As[k][ty * 4]);
            float4 a1 = *reinterpret_cast<const float4*>(&As[k][64 + ty * 4]);
            float4 b0 = *reinterpret_cast<const float4*>(&Bs[k][tx * 4]);
            float4 b1 = *reinterpret_cast<const float4*>(&Bs[k][64 + tx * 4]);
            float a[8] = {a0.x, a0.y, a0.z, a0.w, a1.x, a1.y, a1.z, a1.w};
            float b[8] = {b0.x, b0.y, b0.z, b0.w, b1.x, b1.y, b1.z, b1.w};
            #pragma unroll
            for (int i = 0; i < 8; i++)
                #pragma unroll
                for (int j = 0; j < 8; j++)
                    acc[i][j] = fmaf(a[i], b[j], acc[i][j]);
        }
        __syncthreads();
    }

    #pragma unroll
    for (int i = 0; i < 8; i++) {
        int r = m0 + ((i < 4) ? (ty * 4 + i) : (64 + ty * 4 + (i - 4)));
        if (r >= M) continue;
        #pragma unroll
        for (int j = 0; j < 8; j++) {
            int c = n0 + ((j < 4) ? (tx * 4 + j) : (64 + tx * 4 + (j - 4)));
            if (c >= N) continue;
            float v = acc[i][j] + bias[c];
            if (EPI == 1) { v = fmaxf(v, 0.f); v = v * v; }
            C[(size_t)r * N + c] = v;
        }
    }
}

// ---------------------------------------------------------------------------
// Persistent GRU kernel v2. 48 WGs x 256 threads, W_hh slice in REGISTERS.
// Sync is self-validating data: states pre-filled with NaN canary (0xFF memset);
// writers publish h via relaxed agent-scope atomic stores; readers spin on
// relaxed agent-scope atomic loads until non-canary. No fences, no flags.
// Computed h is a convex combination of tanh/sigmoid outputs -> never NaN.
//
// Thread map: tx = tid&15 (K-slice, 48 contiguous floats of h each),
//             ty = tid>>4 (unit within the WG's 16). Unit gu = 16g + ty.
// Rows owned per thread: {0,1,2}*768 + gu  (gates r,z,n), 48 floats each in
// registers (144 VGPRs). After shfl_xor butterfly over tx, ALL 16 lanes of a
// unit-group hold the full dot -> every lane computes hv redundantly (h_prev
// carried in-register); lane tx==0 stores.
//
// Race-freedom of single h_s buffer: step t+1's poll transitively waits on
// every wave's step-t store, which follows that wave's step-t h_s read.
// ---------------------------------------------------------------------------
__global__ __launch_bounds__(256, 1) void gru_kernel(const float* __restrict__ GX,
                                                     const float* __restrict__ Whh,
                                                     const float* __restrict__ bhh,
                                                     float* __restrict__ states) {
    __shared__ float h_s[HID];
    const int tid = threadIdx.x;
    const int g   = blockIdx.x;          // 0..47
    const int tx  = tid & 15;
    const int ty  = tid >> 4;
    const int gu  = g * 16 + ty;

    // --- W_hh rows into registers (one-time) ---
    float4 W4[3][12];
    #pragma unroll
    for (int p = 0; p < 3; p++) {
        const float* wr = &Whh[(size_t)(p * HID + gu) * HID + 4 * tx];
        #pragma unroll
        for (int j = 0; j < 12; j++)
            W4[p][j] = *reinterpret_cast<const float4*>(&wr[64 * j]);
    }
    float bh[3];
    #pragma unroll
    for (int p = 0; p < 3; p++) bh[p] = bhh[p * HID + gu];

    float hv = 0.f;                       // h_prev for unit gu (carried in-register)
    float gx0 = GX[0 * HID + gu];
    float gx1 = GX[1 * HID + gu];
    float gx2 = GX[2 * HID + gu];

    for (int t = 0; t < SEQ; t++) {
        // prefetch next step's gx early (latency hides under the poll)
        float ngx0 = 0.f, ngx1 = 0.f, ngx2 = 0.f;
        if (t + 1 < SEQ) {
            const float* gp = &GX[(size_t)(t + 1) * G3];
            ngx0 = gp[0 * HID + gu];
            ngx1 = gp[1 * HID + gu];
            ngx2 = gp[2 * HID + gu];
        }

        float4 h4[12];
        if (t > 0) {
            // poll h_{t-1}: this thread owns 3 of the 768 words
            const uint32_t* src = (const uint32_t*)&states[(size_t)(t - 1) * HID];
            uint32_t a0 = CANARY, a1 = CANARY, a2 = CANARY;
            do {
                if (a0 == CANARY) a0 = __hip_atomic_load(&src[tid],       __ATOMIC_RELAXED, __HIP_MEMORY_SCOPE_AGENT);
                if (a1 == CANARY) a1 = __hip_atomic_load(&src[tid + 256], __ATOMIC_RELAXED, __HIP_MEMORY_SCOPE_AGENT);
                if (a2 == CANARY) a2 = __hip_atomic_load(&src[tid + 512], __ATOMIC_RELAXED, __HIP_MEMORY_SCOPE_AGENT);
            } while (a0 == CANARY || a1 == CANARY || a2 == CANARY);
            h_s[tid]       = __uint_as_float(a0);
            h_s[tid + 256] = __uint_as_float(a1);
            h_s[tid + 512] = __uint_as_float(a2);
            __syncthreads();
            #pragma unroll
            for (int j = 0; j < 12; j++)
                h4[j] = *reinterpret_cast<const float4*>(&h_s[4 * tx + 64 * j]);
        } else {
            #pragma unroll
            for (int j = 0; j < 12; j++) h4[j] = make_float4(0.f, 0.f, 0.f, 0.f);
        }

        // matvec: 3 owned rows x this thread's 48-wide K-slice
        float accp[3];
        #pragma unroll
        for (int p = 0; p < 3; p++) {
            float a = 0.f;
            #pragma unroll
            for (int j = 0; j < 12; j++) {
                a = fmaf(W4[p][j].x, h4[j].x, a);
                a = fmaf(W4[p][j].y, h4[j].y, a);
                a = fmaf(W4[p][j].z, h4[j].z, a);
                a = fmaf(W4[p][j].w, h4[j].w, a);
            }
            accp[p] = a;
        }
        // butterfly over the 16 tx lanes -> every lane holds the full sum
        #pragma unroll
        for (int p = 0; p < 3; p++) {
            accp[p] += __shfl_xor(accp[p], 1);
            accp[p] += __shfl_xor(accp[p], 2);
            accp[p] += __shfl_xor(accp[p], 4);
            accp[p] += __shfl_xor(accp[p], 8);
        }

        // gates (all 16 lanes compute identical hv; deterministic arithmetic)
        float hr = accp[0] + bh[0];
        float hz = accp[1] + bh[1];
        float hn = accp[2] + bh[2];
        float r = 1.f / (1.f + expf(-(gx0 + hr)));
        float z = 1.f / (1.f + expf(-(gx1 + hz)));
        float n = tanhf(gx2 + r * hn);
        hv = (1.f - z) * n + z * hv;

        if (tx == 0)
            __hip_atomic_store((uint32_t*)&states[(size_t)t * HID + gu],
                               __float_as_uint(hv),
                               __ATOMIC_RELAXED, __HIP_MEMORY_SCOPE_AGENT);
        gx0 = ngx0; gx1 = ngx1; gx2 = ngx2;
    }
}

// ---------------------------------------------------------------------------
// chunked[c][e] = mean over 64 steps
// ---------------------------------------------------------------------------
__global__ __launch_bounds__(256) void chunkmean_kernel(const float* __restrict__ states,
                                                        float* __restrict__ chunked) {
    int c = blockIdx.x;
    for (int e = threadIdx.x; e < HID; e += 256) {
        float s = 0.f;
        #pragma unroll 8
        for (int i = 0; i < CSZ; i++)
            s += states[(size_t)(c * CSZ + i) * HID + e];
        chunked[c * HID + e] = s * (1.f / 64.f);
    }
}

// ---------------------------------------------------------------------------
// attention: scores[s][c] = dot(qk[s], mk[c])/16, causal chunk mask, softmax
// ---------------------------------------------------------------------------
__global__ void attn_kernel(const float* __restrict__ qk,
                            const float* __restrict__ mk,
                            float* __restrict__ attn) {
    int s = blockIdx.x;
    int lane = threadIdx.x;      // 64 threads
    int c = lane & 31;
    int h = lane >> 5;           // 0/1: split K
    const float* q = &qk[(size_t)s * MDIM];
    const float* m = &mk[(size_t)c * MDIM];
    float sc = 0.f;
    for (int k = h; k < MDIM; k += 2) sc = fmaf(q[k], m[k], sc);
    sc += __shfl_xor(sc, 32);
    sc *= (1.0f / 16.0f);        // 1/sqrt(256)
    bool allowed = (CSZ * c + (CSZ - 1)) < s;
    float v = allowed ? sc : -3.4e38f;
    float mx = v;
    #pragma unroll
    for (int d = 16; d >= 1; d >>= 1) mx = fmaxf(mx, __shfl_xor(mx, d));
    float e = (allowed && mx > -1e37f) ? expf(sc - mx) : 0.f;
    float sm = e;
    #pragma unroll
    for (int d = 16; d >= 1; d >>= 1) sm += __shfl_xor(sm, d);
    float a = (sm > 0.f) ? e / sm : 0.f;
    if (lane < 32) attn[(size_t)s * NCHUNK + c] = a;
}

// ---------------------------------------------------------------------------
// total_partial = base_partial + attn @ chunk_partial; scatter-add into out
// ---------------------------------------------------------------------------
__global__ __launch_bounds__(256) void total_scatter_kernel(const float* __restrict__ bp,
                                                            const float* __restrict__ cp,
                                                            const float* __restrict__ attn,
                                                            const int* __restrict__ uids,
                                                            float* __restrict__ out) {
    int s = blockIdx.x;
    __shared__ float a_s[NCHUNK];
    if (threadIdx.x < NCHUNK) a_s[threadIdx.x] = attn[(size_t)s * NCHUNK + threadIdx.x];
    __syncthreads();
    for (int u = threadIdx.x; u < UDIM; u += 256) {
        float t = bp[(size_t)s * UDIM + u];
        #pragma unroll 8
        for (int c = 0; c < NCHUNK; c++)
            t = fmaf(a_s[c], cp[(size_t)c * UDIM + u], t);
        atomicAdd(&out[(size_t)s * VOC + uids[u]], t);
    }
}

// ---------------------------------------------------------------------------
// launch
// ---------------------------------------------------------------------------
extern "C" void kernel_launch(void* const* d_in, const int* in_sizes, int n_in,
                              void* d_out, int out_size, void* d_ws, size_t ws_size,
                              hipStream_t stream) {
    const int*   ids   = (const int*)d_in[0];
    const int*   uids  = (const int*)d_in[1];
    const float* emb   = (const float*)d_in[2];
    const float* w_ih  = (const float*)d_in[3];
    const float* w_hh  = (const float*)d_in[4];
    const float* b_ih  = (const float*)d_in[5];
    const float* b_hh  = (const float*)d_in[6];
    const float* Wq    = (const float*)d_in[7];
    const float* bq    = (const float*)d_in[8];
    const float* Wk    = (const float*)d_in[9];
    const float* bk    = (const float*)d_in[10];
    const float* Whf   = (const float*)d_in[11];
    const float* bhf   = (const float*)d_in[12];
    const float* Whp   = (const float*)d_in[13];
    const float* bhp   = (const float*)d_in[14];
    const float* Wcv   = (const float*)d_in[15];
    const float* bcv   = (const float*)d_in[16];
    const float* Wph   = (const float*)d_in[17];
    const float* bph   = (const float*)d_in[18];
    const float* obias = (const float*)d_in[19];
    float* out = (float*)d_out;
    float* wsf = (float*)d_ws;

    // workspace layout (floats)
    size_t off = 0;
    float* X      = wsf + off; off += (size_t)SEQ * EMB;       // 2048*512
    float* GX     = wsf + off; off += (size_t)SEQ * G3;        // 2048*2304
    float* states = wsf + off; off += (size_t)SEQ * HID;       // 2048*768
    float* head   = wsf + off; off += (size_t)SEQ * E4;        // 2048*2048
    float* bfeat  = wsf + off; off += (size_t)SEQ * EMB;       // 2048*512
    float* chunk  = wsf + off; off += (size_t)NCHUNK * HID;    // 32*768
    float* qk     = wsf + off; off += (size_t)SEQ * MDIM;      // 2048*256
    float* mk     = wsf + off; off += (size_t)NCHUNK * MDIM;   // 32*256
    float* cv     = wsf + off; off += (size_t)NCHUNK * EMB;    // 32*512
    float* cp     = wsf + off; off += (size_t)NCHUNK * UDIM;   // 32*2048
    float* bp     = wsf + off; off += (size_t)SEQ * UDIM;      // 2048*2048
    float* attn   = wsf + off; off += (size_t)SEQ * NCHUNK;    // 2048*32

    // 1) embedding gather
    embed_kernel<<<SEQ, 256, 0, stream>>>(ids, emb, X);
    // 2) GX = X @ w_ih^T + b_ih   [2048, 2304], K=512
    gemm_nt<0><<<dim3(G3 / 128, SEQ / 128), 256, 0, stream>>>(X, w_ih, b_ih, GX, SEQ, G3, EMB);
    // 3) canary-fill states (0xFF bytes = -NaN), then persistent GRU
    hipMemsetAsync(states, 0xFF, (size_t)SEQ * HID * sizeof(float), stream);
    gru_kernel<<<G_GRU, 256, 0, stream>>>(GX, w_hh, b_hh, states);
    // 4) chunk means
    chunkmean_kernel<<<NCHUNK, 256, 0, stream>>>(states, chunk);
    // 5) projections
    gemm_nt<0><<<dim3(MDIM / 128, SEQ / 128), 256, 0, stream>>>(states, Wq, bq, qk, SEQ, MDIM, HID);
    gemm_nt<0><<<dim3(MDIM / 128, 1), 256, 0, stream>>>(chunk, Wk, bk, mk, NCHUNK, MDIM, HID);
    gemm_nt<1><<<dim3(E4 / 128, SEQ / 128), 256, 0, stream>>>(states, Whf, bhf, head, SEQ, E4, HID);
    gemm_nt<0><<<dim3(EMB / 128, SEQ / 128), 256, 0, stream>>>(head, Whp, bhp, bfeat, SEQ, EMB, E4);
    gemm_nt<0><<<dim3(EMB / 128, 1), 256, 0, stream>>>(chunk, Wcv, bcv, cv, NCHUNK, EMB, HID);
    gemm_nt<0><<<dim3(UDIM / 128, 1), 256, 0, stream>>>(cv, Wph, bph, cp, NCHUNK, UDIM, EMB);
    gemm_nt<0><<<dim3(UDIM / 128, SEQ / 128), 256, 0, stream>>>(bfeat, Wph, bph, bp, SEQ, UDIM, EMB);
    // 6) base_logits -> d_out (full overwrite each call)
    gemm_nt<0><<<dim3((VOC + 127) / 128, SEQ / 128), 256, 0, stream>>>(bfeat, emb, obias, out, SEQ, VOC, EMB);
    // 7) attention weights
    attn_kernel<<<SEQ, 64, 0, stream>>>(qk, mk, attn);
    // 8) total partial + scatter-add
    total_scatter_kernel<<<SEQ, 256, 0, stream>>>(bp, cp, attn, uids, out);
}